// Round 7
// baseline (30.326 us; speedup 1.0000x reference)
//
#include <hip/hip_runtime.h>

#define SEQ 128
#define SD  15
#define REC 32    // floats per (b,s) record in dba_params
#define RPB 4     // rows per block
#define NT  (RPB * SEQ)   // 512 threads, 8 waves

// ---------------------------------------------------------------------------
// Single fused kernel. Block = 4 batch rows.
//  P1: thread (row,s) loads record head (32 B of one 64 B line -> FETCH is
//      the 33 MB line-granularity minimum), stores pre-scaled dq -> LDS,
//      shuffle-scans positions in registers.
//  P2: lanes 0..3 of wave 0 each run one row's 127-step quaternion chain from
//      LDS through an 8-deep register ring; tree-form norm shortens the
//      serial dependency (~26 cyc/step -> ~1.4 us total).
//  P3: every thread writes its full 15-float record in ONE phase — each
//      output line is touched in a single burst, written to HBM exactly once
//      (R5's split zero-write/pos-write doubled WRITE to 60.8 MB).
// ---------------------------------------------------------------------------
__global__ __launch_bounds__(NT, 8) void fused_kernel(const float* __restrict__ dba,
                                                      const float* __restrict__ gt,
                                                      float* __restrict__ out,
                                                      int B) {
    const int tid  = threadIdx.x;
    const int row  = tid >> 7;          // 0..3
    const int s    = tid & (SEQ - 1);   // 0..127
    const int lane = tid & 63;
    const int half = s >> 6;            // which of the row's two waves
    const int r    = blockIdx.x * RPB + row;
    const bool valid = (r < B);

    __shared__ float4 sdq  [RPB][SEQ + 1];   // +1 pad keeps chain lanes on distinct banks
    __shared__ float4 squat[RPB][SEQ + 1];
    __shared__ float  ginit[RPB][8];
    __shared__ float  w0tot[RPB][3];

    // ---- P1: loads + pos scan ----
    float d0 = 0.f, d1 = 0.f, d2 = 0.f;
    if (valid) {
        const float* rec = dba + ((size_t)r * SEQ + s) * REC;
        const float4 h0 = *reinterpret_cast<const float4*>(rec);
        const float4 h1 = *reinterpret_cast<const float4*>(rec + 4);
        sdq[row][s] = make_float4(h0.w * 0.1f, h1.x * 0.1f, h1.y * 0.1f, h1.z * 0.1f);
        d0 = h0.x * 0.1f; d1 = h0.y * 0.1f; d2 = h0.z * 0.1f;
        if (s == 0) {
            const float* g = gt + (size_t)r * SEQ * SD;
            *reinterpret_cast<float4*>(&ginit[row][0]) = *reinterpret_cast<const float4*>(g);
            *reinterpret_cast<float4*>(&ginit[row][4]) = *reinterpret_cast<const float4*>(g + 4);
        }
    }

    float ix = d0, iy = d1, iz = d2;       // wave-local inclusive scan
#pragma unroll
    for (int off = 1; off < 64; off <<= 1) {
        const float tx = __shfl_up(ix, off, 64);
        const float ty = __shfl_up(iy, off, 64);
        const float tz = __shfl_up(iz, off, 64);
        if (lane >= off) { ix += tx; iy += ty; iz += tz; }
    }
    if (half == 0 && lane == 63) {
        w0tot[row][0] = ix; w0tot[row][1] = iy; w0tot[row][2] = iz;
    }
    __syncthreads();
    if (half == 1) { ix += w0tot[row][0]; iy += w0tot[row][1]; iz += w0tot[row][2]; }

    // ---- P2: quaternion chains, 4 lanes of wave 0 ----
    if (tid < RPB && blockIdx.x * RPB + tid < B) {
        const float4* srow = sdq[tid];
        float4*       qrow = squat[tid];
        float q0 = ginit[tid][3], q1 = ginit[tid][4],
              q2 = ginit[tid][5], q3 = ginit[tid][6];
        qrow[0] = make_float4(q0, q1, q2, q3);     // t=0: init_q, NOT normalized

        float4 ring[8];
#pragma unroll
        for (int u = 0; u < 8; ++u) ring[u] = srow[u];

        // 15 windows of 8 steps (t = 1..120), refilling one window ahead;
        // last refill index = 14*8+7+8 = 127 (in-bounds).
        for (int w = 0; w < 15; ++w) {
#pragma unroll
            for (int u = 0; u < 8; ++u) {
                const int t = w * 8 + u + 1;
                q0 += ring[u].x; q1 += ring[u].y; q2 += ring[u].z; q3 += ring[u].w;
                ring[u] = srow[w * 8 + u + 8];
                const float a = q0 * q0 + q1 * q1;       // tree norm: 2 indep
                const float b = q2 * q2 + q3 * q3;       // fma chains + 1 add
                const float inv = __builtin_amdgcn_rsqf(a + b);
                q0 *= inv; q1 *= inv; q2 *= inv; q3 *= inv;
                qrow[t] = make_float4(q0, q1, q2, q3);
            }
        }
#pragma unroll
        for (int u = 0; u < 7; ++u) {              // tail t = 121..127
            const int t = 121 + u;
            q0 += ring[u].x; q1 += ring[u].y; q2 += ring[u].z; q3 += ring[u].w;
            const float a = q0 * q0 + q1 * q1;
            const float b = q2 * q2 + q3 * q3;
            const float inv = __builtin_amdgcn_rsqf(a + b);
            q0 *= inv; q1 *= inv; q2 *= inv; q3 *= inv;
            qrow[t] = make_float4(q0, q1, q2, q3);
        }
    }
    __syncthreads();

    // ---- P3: full-record stores, one phase, each line written once ----
    if (valid) {
        const float4 q = squat[row][s];
        float* o = out + ((size_t)r * SEQ + s) * SD;
        o[0] = ginit[row][0] + ix - d0;   // exclusive prefix = inclusive - own
        o[1] = ginit[row][1] + iy - d1;
        o[2] = ginit[row][2] + iz - d2;
        o[3] = q.x; o[4] = q.y; o[5] = q.z; o[6] = q.w;
#pragma unroll
        for (int k = 7; k < SD; ++k) o[k] = 0.f;
    }
}

extern "C" void kernel_launch(void* const* d_in, const int* in_sizes, int n_in,
                              void* d_out, int out_size, void* d_ws, size_t ws_size,
                              hipStream_t stream) {
    const float* dba = (const float*)d_in[0];   // (B, 128, 32)
    // d_in[1] = imu_measurements — unused by the reference
    const float* gt  = (const float*)d_in[2];   // (B, 128, 15)
    float* out = (float*)d_out;                 // (B, 128, 15)

    const int B = in_sizes[0] / (SEQ * REC);
    const int blocks = (B + RPB - 1) / RPB;
    fused_kernel<<<blocks, NT, 0, stream>>>(dba, gt, out, B);
}